// Round 3
// baseline (116.946 us; speedup 1.0000x reference)
//
#include <hip/hip_runtime.h>
#include <math.h>

#define BB 4
#define S 8192
#define C 256
#define NW 2048
#define WS 256
#define PSZ 256
#define DD 32
#define KK 65
#define TOTW (BB * NW) /* 8192 */

// ---------------------------------------------------------------------------
// Kernel 0: transpose W_p [PSZ][WS] -> WpT [WS][PSZ]
// ---------------------------------------------------------------------------
__global__ __launch_bounds__(256) void wp_transpose(const float* __restrict__ Wp,
                                                    float* __restrict__ WpT) {
    int p = blockIdx.x;
    int ws = threadIdx.x;
    WpT[ws * PSZ + p] = Wp[p * WS + ws];
}

// ---------------------------------------------------------------------------
// Kernel 1: per-window precompute.
//   g[w][c] = sum_ws c_t[w][ws] * W_a[ws][c]
//   p_t[w]  = S * sigmoid( sum_p tanh(c_t @ W_p^T)[p] * V_p[p] )
// 16 windows/block, 512 blocks (2/CU). v2: REGISTER PREFETCH of the next
// iteration's 8 weight values — the 128 FMAs (256 issue cycles) now cover the
// ~200-cycle L2 load latency, which was the R2 stall (VALUBusy 40%).
// ---------------------------------------------------------------------------
__global__ __launch_bounds__(256) void precomp(const float* __restrict__ ct,
                                               const float* __restrict__ WpT,
                                               const float* __restrict__ Wa,
                                               const float* __restrict__ Vp,
                                               float* __restrict__ g,
                                               float* __restrict__ pt) {
    __shared__ __align__(16) float ctl[16][WS];
    __shared__ float red[16][4];

    const int tid = threadIdx.x;
    const int wbase = blockIdx.x * 16;

    {
        const float4* src = (const float4*)(ct + (size_t)wbase * WS);
        float4* dst = (float4*)(&ctl[0][0]);
#pragma unroll
        for (int i = 0; i < 4; i++) dst[tid + i * 256] = src[tid + i * 256];
    }
    __syncthreads();

    float hacc[16], gacc[16];
#pragma unroll
    for (int r = 0; r < 16; r++) { hacc[r] = 0.f; gacc[r] = 0.f; }

    float wpc[4], wac[4], wpn[4], wan[4];
#pragma unroll
    for (int j = 0; j < 4; j++) {
        wpc[j] = WpT[j * PSZ + tid];
        wac[j] = Wa[j * C + tid];
    }

    for (int ws = 0; ws < WS; ws += 4) {
        const int wsn = ws + 4;
        if (wsn < WS) {
#pragma unroll
            for (int j = 0; j < 4; j++) {
                wpn[j] = WpT[(wsn + j) * PSZ + tid];
                wan[j] = Wa[(wsn + j) * C + tid];
            }
        }
#pragma unroll
        for (int r = 0; r < 16; r++) {
            const float4 c4 = *(const float4*)&ctl[r][ws];   // uniform-addr LDS broadcast
            hacc[r] = fmaf(c4.x, wpc[0], hacc[r]);
            hacc[r] = fmaf(c4.y, wpc[1], hacc[r]);
            hacc[r] = fmaf(c4.z, wpc[2], hacc[r]);
            hacc[r] = fmaf(c4.w, wpc[3], hacc[r]);
            gacc[r] = fmaf(c4.x, wac[0], gacc[r]);
            gacc[r] = fmaf(c4.y, wac[1], gacc[r]);
            gacc[r] = fmaf(c4.z, wac[2], gacc[r]);
            gacc[r] = fmaf(c4.w, wac[3], gacc[r]);
        }
#pragma unroll
        for (int j = 0; j < 4; j++) { wpc[j] = wpn[j]; wac[j] = wan[j]; }
    }

#pragma unroll
    for (int r = 0; r < 16; r++) g[(size_t)(wbase + r) * C + tid] = gacc[r];

    const int lane = tid & 63, wv = tid >> 6;
    const float vp = Vp[tid];
#pragma unroll
    for (int r = 0; r < 16; r++) {
        float v = tanhf(hacc[r]) * vp;
#pragma unroll
        for (int off = 32; off >= 1; off >>= 1) v += __shfl_xor(v, off);
        if (lane == 0) red[r][wv] = v;
    }
    __syncthreads();
    if (tid < 16) {
        const float x = red[tid][0] + red[tid][1] + red[tid][2] + red[tid][3];
        const float sig = 1.f / (1.f + expf(-x));
        pt[wbase + tid] = (float)S * sig;
    }
}

// ---------------------------------------------------------------------------
// Kernel 2: gather-attention, one wave per window (unchanged from R2).
// ---------------------------------------------------------------------------
__global__ __launch_bounds__(256) void attn(const float* __restrict__ q,
                                            const float* __restrict__ g,
                                            const float* __restrict__ pt,
                                            float* __restrict__ out) {
    const int tid = threadIdx.x;
    const int lane = tid & 63;
    const int wv = tid >> 6;
    const int wg = (blockIdx.x << 2) | wv;     // global window
    const int b = wg >> 11;                    // NW = 2048
    const int grp = lane >> 4;                 // key sub-slot
    const int sub = lane & 15;                 // channel group

    const float p = pt[wg];
    const int s0 = (int)p;                     // trunc == floor (p > 0)

    const float* grow = g + (size_t)wg * C + sub * 4;
    const float4 g0 = *(const float4*)(grow);
    const float4 g1 = *(const float4*)(grow + 64);
    const float4 g2 = *(const float4*)(grow + 128);
    const float4 g3 = *(const float4*)(grow + 192);

    const float* qb = q + (size_t)b * S * C + sub * 4;

    float m = -1e30f, den = 0.f;
    float4 a0 = {0, 0, 0, 0}, a1 = {0, 0, 0, 0}, a2 = {0, 0, 0, 0}, a3 = {0, 0, 0, 0};

    for (int it = 0; it < 17; it++) {
        const int k = it * 4 + grp;
        const int s = s0 + k - DD;
        const bool valid = (k <= 64) && ((unsigned)s < (unsigned)S);
        const int srow = min(max(s, 0), S - 1);

        const float* qr = qb + (size_t)srow * C;
        const float4 q0 = *(const float4*)(qr);
        const float4 q1 = *(const float4*)(qr + 64);
        const float4 q2 = *(const float4*)(qr + 128);
        const float4 q3 = *(const float4*)(qr + 192);

        float d = q0.x * g0.x;
        d = fmaf(q0.y, g0.y, d); d = fmaf(q0.z, g0.z, d); d = fmaf(q0.w, g0.w, d);
        d = fmaf(q1.x, g1.x, d); d = fmaf(q1.y, g1.y, d);
        d = fmaf(q1.z, g1.z, d); d = fmaf(q1.w, g1.w, d);
        d = fmaf(q2.x, g2.x, d); d = fmaf(q2.y, g2.y, d);
        d = fmaf(q2.z, g2.z, d); d = fmaf(q2.w, g2.w, d);
        d = fmaf(q3.x, g3.x, d); d = fmaf(q3.y, g3.y, d);
        d = fmaf(q3.z, g3.z, d); d = fmaf(q3.w, g3.w, d);
#pragma unroll
        for (int off = 8; off >= 1; off >>= 1) d += __shfl_xor(d, off);

        d = valid ? d : -3e38f;

        const float fs = (float)s - p;
        const float t = fs * (1.f / (float)DD);
        const float lg = -2.f * t * t;

        const float mn = fmaxf(m, d);
        const float sc = __expf(m - mn);       // rescale old state
        const float e  = __expf(d - mn);       // denominator term
        const float eg = __expf(d - mn + lg);  // numerator term (exp * gauss)
        den = fmaf(den, sc, e);
        m = mn;

        a0.x = fmaf(eg, q0.x, a0.x * sc); a0.y = fmaf(eg, q0.y, a0.y * sc);
        a0.z = fmaf(eg, q0.z, a0.z * sc); a0.w = fmaf(eg, q0.w, a0.w * sc);
        a1.x = fmaf(eg, q1.x, a1.x * sc); a1.y = fmaf(eg, q1.y, a1.y * sc);
        a1.z = fmaf(eg, q1.z, a1.z * sc); a1.w = fmaf(eg, q1.w, a1.w * sc);
        a2.x = fmaf(eg, q2.x, a2.x * sc); a2.y = fmaf(eg, q2.y, a2.y * sc);
        a2.z = fmaf(eg, q2.z, a2.z * sc); a2.w = fmaf(eg, q2.w, a2.w * sc);
        a3.x = fmaf(eg, q3.x, a3.x * sc); a3.y = fmaf(eg, q3.y, a3.y * sc);
        a3.z = fmaf(eg, q3.z, a3.z * sc); a3.w = fmaf(eg, q3.w, a3.w * sc);
    }

    // merge the 4 groups (cross-lane butterfly; m/den uniform within group)
    float M = m;
    M = fmaxf(M, __shfl_xor(M, 16));
    M = fmaxf(M, __shfl_xor(M, 32));
    const float scg = __expf(m - M);

    den *= scg;
    den += __shfl_xor(den, 16);
    den += __shfl_xor(den, 32);

#define MERGE(v) { v *= scg; v += __shfl_xor(v, 16); v += __shfl_xor(v, 32); }
    MERGE(a0.x) MERGE(a0.y) MERGE(a0.z) MERGE(a0.w)
    MERGE(a1.x) MERGE(a1.y) MERGE(a1.z) MERGE(a1.w)
    MERGE(a2.x) MERGE(a2.y) MERGE(a2.z) MERGE(a2.w)
    MERGE(a3.x) MERGE(a3.y) MERGE(a3.z) MERGE(a3.w)
#undef MERGE

    float4 o = a0;
    if (grp == 1) o = a1;
    else if (grp == 2) o = a2;
    else if (grp == 3) o = a3;

    const float r = 1.f / den;
    o.x *= r; o.y *= r; o.z *= r; o.w *= r;

    *(float4*)(out + (size_t)wg * C + lane * 4) = o;
}

// ---------------------------------------------------------------------------
extern "C" void kernel_launch(void* const* d_in, const int* in_sizes, int n_in,
                              void* d_out, int out_size, void* d_ws, size_t ws_size,
                              hipStream_t stream) {
    const float* q  = (const float*)d_in[0];
    const float* ct = (const float*)d_in[1];
    const float* Wa = (const float*)d_in[2];
    const float* Wp = (const float*)d_in[3];
    const float* Vp = (const float*)d_in[4];
    float* out = (float*)d_out;

    char* ws = (char*)d_ws;
    float* WpT = (float*)ws;                          // 256 KB
    float* pt  = (float*)(ws + 262144);               // 32 KB
    float* g   = (float*)(ws + 262144 + 32768);       // 8 MB

    wp_transpose<<<PSZ, WS, 0, stream>>>(Wp, WpT);
    precomp<<<TOTW / 16, 256, 0, stream>>>(ct, WpT, Wa, Vp, g, pt);
    attn<<<TOTW / 4, 256, 0, stream>>>(q, g, pt, out);
}